// Round 13
// baseline (51.733 us; speedup 1.0000x reference)
//
#include <hip/hip_runtime.h>
#include <hip/hip_bf16.h>

#define BB 8
#define NN 2048
#define EE 64
#define DD 128
#define BN (BB * NN)

typedef __attribute__((ext_vector_type(8))) short short8v;
typedef __attribute__((ext_vector_type(4))) float float4v;

__device__ __forceinline__ short f2bf(float f) {
    __hip_bfloat16 h = __float2bfloat16(f);
    return *reinterpret_cast<short*>(&h);
}
__device__ __forceinline__ uint32_t pack2bf(float a, float b) {
    return (uint32_t)(uint16_t)f2bf(a) | ((uint32_t)(uint16_t)f2bf(b) << 16);
}

// ---------------- fused prep: embq | zq | sq ----------------
__global__ __launch_bounds__(256) void prep_kernel(const float* __restrict__ emb,
                                                   const float* __restrict__ z,
                                                   short* __restrict__ embq,
                                                   short* __restrict__ zq,
                                                   float* __restrict__ sq) {
    __shared__ float zl[64 * 129];
    const int bid = blockIdx.x;
    const int t = threadIdx.x;

    if (bid < 512) {
        int gid = bid * 256 + t;
        int s = gid & 63;
        int ke = (gid >> 6) & 1;
        int r16 = (gid >> 7) & 127;
        int b = gid >> 14;
        int i = r16 * 16 + (s & 15);
        int e0 = ke * 32 + ((s >> 4) & 3) * 8;
        const float4* src = reinterpret_cast<const float4*>(emb + ((size_t)(b * NN + i)) * EE + e0);
        float4 v0 = src[0], v1 = src[1];
        short8v o;
        o[0] = f2bf(v0.x); o[1] = f2bf(v0.y); o[2] = f2bf(v0.z); o[3] = f2bf(v0.w);
        o[4] = f2bf(v1.x); o[5] = f2bf(v1.y); o[6] = f2bf(v1.z); o[7] = f2bf(v1.w);
        *reinterpret_cast<short8v*>(embq + (size_t)gid * 8) = o;
    } else if (bid < 768) {
        int v = bid - 512;  // b*32 + jt
        int b = v >> 5;
        int jt = v & 31;
        int jb = jt * 64;
#pragma unroll
        for (int k = 0; k < 8; ++k) {
            int idx = t + k * 256;
            int jl = idx >> 5, c4 = idx & 31;
            float4 w = reinterpret_cast<const float4*>(z + ((size_t)(b * NN + jb + jl)) * DD)[c4];
            float* p = &zl[jl * 129 + c4 * 4];
            p[0] = w.x; p[1] = w.y; p[2] = w.z; p[3] = w.w;
        }
        __syncthreads();
#pragma unroll
        for (int k = 0; k < 4; ++k) {
            int sid = t + k * 256;
            int blk = sid >> 6, s = sid & 63;
            int ktl = blk >> 3, nt = blk & 7;
            int d = nt * 16 + (s & 15);
            int jl = ktl * 32 + ((s >> 4) & 3) * 8;
            short8v o;
#pragma unroll
            for (int e = 0; e < 8; ++e) o[e] = f2bf(zl[(jl + e) * 129 + d]);
            *reinterpret_cast<short8v*>(zq + ((size_t)((b * 64 + jt * 2 + ktl) * 8 + nt) * 64 + s) * 8) = o;
        }
    } else {
        int v = bid - 768;
        int q = t & 15;
#pragma unroll
        for (int p = 0; p < 4; ++p) {
            int row = v * 64 + p * 16 + (t >> 4);
            float4 rv = reinterpret_cast<const float4*>(emb + (size_t)row * EE)[q];
            float a0 = __bfloat162float(__float2bfloat16(rv.x));
            float a1 = __bfloat162float(__float2bfloat16(rv.y));
            float a2 = __bfloat162float(__float2bfloat16(rv.z));
            float a3 = __bfloat162float(__float2bfloat16(rv.w));
            float s2 = a0 * a0 + a1 * a1 + a2 * a2 + a3 * a3;
#pragma unroll
            for (int off = 1; off < 16; off <<= 1) s2 += __shfl_xor(s2, off);
            if (q == 0) sq[row] = s2;
        }
    }
}

// ---------------- main MFMA attention: barrier-free streaming ----------------
// INSTRUMENTED ROUND: the j-loop runs `rep` passes. acc and dsum accumulate rep
// identical passes -> num and den both scale by rep -> out = num/den unchanged.
// rep=4 makes the attn dispatch ~4x longer so it surfaces in rocprof top-5 with
// counters, and (total - base)/3 gives the true single-pass attn time.
__global__ __launch_bounds__(256, 2) void attn_mfma(const short* __restrict__ embq,
                                                    const short* __restrict__ zq,
                                                    const float* __restrict__ sq,
                                                    float* __restrict__ outnum,
                                                    float* __restrict__ den,
                                                    int njs, int rep) {
    __shared__ short sU[4][2048];  // 16KB: per-wave P^T scratch only (wave-private)

    const int t = threadIdx.x;
    const int bid = blockIdx.x;
    const int b = bid & 7;
    const int q = bid >> 3;
    const int it = q & 15;
    const int js = q >> 4;
    const int ib = it * 128;
    const int w = t >> 6;
    const int l = t & 63;
    const int g = (l >> 4) & 3;
    const int c = l & 15;

    const short8v* embq8 = (const short8v*)embq;
    const short8v* zq8 = (const short8v*)zq;
    const float* sqB = sq + b * NN;

    const int ntiles = 32 / njs;
    const int jt0 = js * ntiles;
    const int jtEnd = jt0 + ntiles;

    // this wave's I fragments (B operand of swapped QK), straight from global
    short8v qkB[2][2];
#pragma unroll
    for (int m = 0; m < 2; ++m)
#pragma unroll
        for (int ke = 0; ke < 2; ++ke)
            qkB[m][ke] = embq8[((size_t)(b * 128 + it * 8 + w * 2 + m) * 2 + ke) * 64 + l];
    float sqi[2];
#pragma unroll
    for (int m = 0; m < 2; ++m) sqi[m] = sqB[ib + w * 32 + m * 16 + c];

    float dsum[2] = {0.f, 0.f};
    float4v acc[2][8];
#pragma unroll
    for (int m = 0; m < 2; ++m)
#pragma unroll
        for (int nt = 0; nt < 8; ++nt) acc[m][nt] = (float4v){0.f, 0.f, 0.f, 0.f};

    char* ptw = (char*)&sU[w][0];
    const int swz = (c & 7) << 4;

    for (int rr = 0; rr < rep; ++rr) {
    for (int jt = jt0; jt < jtEnd; ++jt) {
        // ---- issue all of this tile's loads up front (L2 hits, ILP) ----
        short8v a[4][2];
        float4 sqj[4];
#pragma unroll
        for (int J = 0; J < 4; ++J) {
            a[J][0] = embq8[((size_t)(b * 128 + jt * 4 + J) * 2 + 0) * 64 + l];
            a[J][1] = embq8[((size_t)(b * 128 + jt * 4 + J) * 2 + 1) * 64 + l];
            sqj[J] = *reinterpret_cast<const float4*>(sqB + jt * 64 + J * 16 + 4 * g);
        }

        bool anyLive = false;
#pragma unroll
        for (int J = 0; J < 4; ++J) {
            float d2[2][4];
            float mn = 1e30f;
#pragma unroll
            for (int m = 0; m < 2; ++m) {
                float4v sfr = (float4v){0.f, 0.f, 0.f, 0.f};
                sfr = __builtin_amdgcn_mfma_f32_16x16x32_bf16(a[J][0], qkB[m][0], sfr, 0, 0, 0);
                sfr = __builtin_amdgcn_mfma_f32_16x16x32_bf16(a[J][1], qkB[m][1], sfr, 0, 0, 0);
                d2[m][0] = fmaxf(fmaf(-2.0f, sfr[0], sqi[m] + sqj[J].x), 0.0f);
                d2[m][1] = fmaxf(fmaf(-2.0f, sfr[1], sqi[m] + sqj[J].y), 0.0f);
                d2[m][2] = fmaxf(fmaf(-2.0f, sfr[2], sqi[m] + sqj[J].z), 0.0f);
                d2[m][3] = fmaxf(fmaf(-2.0f, sfr[3], sqi[m] + sqj[J].w), 0.0f);
                mn = fminf(mn, fminf(fminf(d2[m][0], d2[m][1]), fminf(d2[m][2], d2[m][3])));
            }
            const bool live = !__all(mn > 13.8f);  // wave-uniform
#pragma unroll
            for (int m = 0; m < 2; ++m) {
                unsigned long long pword = 0ull;
                if (live) {
                    float p0 = __expf(-d2[m][0]);
                    float p1 = __expf(-d2[m][1]);
                    float p2 = __expf(-d2[m][2]);
                    float p3 = __expf(-d2[m][3]);
                    dsum[m] += (p0 + p1) + (p2 + p3);
                    pword = (unsigned long long)pack2bf(p0, p1) |
                            ((unsigned long long)pack2bf(p2, p3) << 32);
                }
                // must write even when dead: PV (if tile live) reads every slot
                *reinterpret_cast<unsigned long long*>(
                    ptw + ((m * 2048 + c * 128 + g * 8) ^ swz ^ (J * 32))) = pword;
            }
            anyLive |= live;
        }

        // ---- PV only when some J in this tile carries mass ----
        if (anyLive) {
            short8v pa[2][2];
#pragma unroll
            for (int m = 0; m < 2; ++m)
#pragma unroll
                for (int kt = 0; kt < 2; ++kt)
                    pa[m][kt] = *reinterpret_cast<const short8v*>(
                        ptw + ((m * 2048 + c * 128 + kt * 64 + g * 16) ^ swz));
#pragma unroll
            for (int nt = 0; nt < 8; ++nt) {
                short8v z0 = zq8[(size_t)((b * 64 + jt * 2 + 0) * 8 + nt) * 64 + l];
                short8v z1 = zq8[(size_t)((b * 64 + jt * 2 + 1) * 8 + nt) * 64 + l];
#pragma unroll
                for (int m = 0; m < 2; ++m) {
                    acc[m][nt] = __builtin_amdgcn_mfma_f32_16x16x32_bf16(pa[m][0], z0, acc[m][nt], 0, 0, 0);
                    acc[m][nt] = __builtin_amdgcn_mfma_f32_16x16x32_bf16(pa[m][1], z1, acc[m][nt], 0, 0, 0);
                }
            }
        }
    }
    }

    // dsum reduce over g-groups -> all lanes hold row (m, c) sums
#pragma unroll
    for (int m = 0; m < 2; ++m) {
        dsum[m] += __shfl_xor(dsum[m], 16);
        dsum[m] += __shfl_xor(dsum[m], 32);
    }

    if (njs == 1) {
#pragma unroll
        for (int m = 0; m < 2; ++m) {
            float invr[4];
#pragma unroll
            for (int r = 0; r < 4; ++r) invr[r] = 1.0f / __shfl(dsum[m], 4 * g + r);
#pragma unroll
            for (int r = 0; r < 4; ++r) {
                size_t row = (size_t)(b * NN + ib + w * 32 + m * 16 + 4 * g + r);
#pragma unroll
                for (int nt = 0; nt < 8; ++nt)
                    outnum[row * DD + nt * 16 + c] = acc[m][nt][r] * invr[r];
            }
        }
    } else {
        if (l < 16) {
            den[(size_t)js * BN + b * NN + ib + w * 32 + l] = dsum[0];
            den[(size_t)js * BN + b * NN + ib + w * 32 + 16 + l] = dsum[1];
        }
        // skip num writes when this wave's whole j-slice carries no mass
        if (!__all(fmaxf(dsum[0], dsum[1]) < 1e-6f)) {
#pragma unroll
            for (int m = 0; m < 2; ++m)
#pragma unroll
                for (int r = 0; r < 4; ++r) {
                    size_t row = (size_t)js * BN + b * NN + ib + w * 32 + m * 16 + 4 * g + r;
#pragma unroll
                    for (int nt = 0; nt < 8; ++nt)
                        outnum[row * DD + nt * 16 + c] = acc[m][nt][r];
                }
        }
    }
}

// ---------------- reduce: out = sum_js num / sum_js den, num reads gated by den ----------------
__global__ __launch_bounds__(256) void reduce_kernel(const float4* __restrict__ num,
                                                     const float* __restrict__ den,
                                                     float4* __restrict__ out,
                                                     int njs) {
    int i4 = blockIdx.x * 256 + threadIdx.x;
    int row = i4 >> 5;
    float4 ns = make_float4(0.f, 0.f, 0.f, 0.f);
    float ds = 0.f;
    for (int js = 0; js < njs; ++js) {
        float dj = den[(size_t)js * BN + row];
        ds += dj;
        if (dj >= 1e-6f) {
            float4 v = num[(size_t)js * ((size_t)BN * (DD / 4)) + i4];
            ns.x += v.x; ns.y += v.y; ns.z += v.z; ns.w += v.w;
        }
    }
    float inv = 1.0f / ds;
    out[i4] = make_float4(ns.x * inv, ns.y * inv, ns.z * inv, ns.w * inv);
}

extern "C" void kernel_launch(void* const* d_in, const int* in_sizes, int n_in,
                              void* d_out, int out_size, void* d_ws, size_t ws_size,
                              hipStream_t stream) {
    (void)in_sizes; (void)n_in; (void)out_size;
    const float* emb = (const float*)d_in[0];
    const float* z = (const float*)d_in[1];
    float* out = (float*)d_out;
    float* ws = (float*)d_ws;

    // ws layout (floats): sq[BN] | den[njs*BN] | num[njs*BN*DD] | embq(1M shorts) | zq(2M shorts)
    int njs = 1;
    if (ws_size >= 40ull * 1024 * 1024) njs = 4;
    else if (ws_size >= 24ull * 1024 * 1024) njs = 2;

    float* sqw = ws;
    float* denw = ws + BN;
    float* numw = denw + (size_t)njs * BN;
    size_t numFloats = (njs > 1) ? (size_t)njs * BN * DD : 0;
    short* embqw = (short*)(numw + numFloats);
    short* zqw = embqw + (size_t)BB * NN * EE;

    prep_kernel<<<1024, 256, 0, stream>>>(emb, z, embqw, zqw, sqw);

    // rep=4: instrumentation multiplier (num/den scale together; out unchanged)
    attn_mfma<<<8 * 16 * njs, 256, 0, stream>>>(embqw, zqw, sqw,
                                                njs == 1 ? out : numw, denw, njs, 4);

    if (njs > 1) {
        reduce_kernel<<<(BN * (DD / 4)) / 256, 256, 0, stream>>>(
            (const float4*)numw, denw, (float4*)out, njs);
    }
}

// Round 16
// 43.684 us; speedup vs baseline: 1.1843x; 1.1843x over previous
//
#include <hip/hip_runtime.h>
#include <hip/hip_bf16.h>

#define BB 8
#define NN 2048
#define EE 64
#define DD 128
#define BN (BB * NN)

typedef __attribute__((ext_vector_type(8))) short short8v;
typedef __attribute__((ext_vector_type(4))) float float4v;

__device__ __forceinline__ short f2bf(float f) {
    __hip_bfloat16 h = __float2bfloat16(f);
    return *reinterpret_cast<short*>(&h);
}
__device__ __forceinline__ uint32_t pack2bf(float a, float b) {
    return (uint32_t)(uint16_t)f2bf(a) | ((uint32_t)(uint16_t)f2bf(b) << 16);
}

// ---------------- fused prep: embq | zq | sq ----------------
__global__ __launch_bounds__(256) void prep_kernel(const float* __restrict__ emb,
                                                   const float* __restrict__ z,
                                                   short* __restrict__ embq,
                                                   short* __restrict__ zq,
                                                   float* __restrict__ sq) {
    __shared__ float zl[64 * 129];
    const int bid = blockIdx.x;
    const int t = threadIdx.x;

    if (bid < 512) {
        int gid = bid * 256 + t;
        int s = gid & 63;
        int ke = (gid >> 6) & 1;
        int r16 = (gid >> 7) & 127;
        int b = gid >> 14;
        int i = r16 * 16 + (s & 15);
        int e0 = ke * 32 + ((s >> 4) & 3) * 8;
        const float4* src = reinterpret_cast<const float4*>(emb + ((size_t)(b * NN + i)) * EE + e0);
        float4 v0 = src[0], v1 = src[1];
        short8v o;
        o[0] = f2bf(v0.x); o[1] = f2bf(v0.y); o[2] = f2bf(v0.z); o[3] = f2bf(v0.w);
        o[4] = f2bf(v1.x); o[5] = f2bf(v1.y); o[6] = f2bf(v1.z); o[7] = f2bf(v1.w);
        *reinterpret_cast<short8v*>(embq + (size_t)gid * 8) = o;
    } else if (bid < 768) {
        int v = bid - 512;  // b*32 + jt
        int b = v >> 5;
        int jt = v & 31;
        int jb = jt * 64;
#pragma unroll
        for (int k = 0; k < 8; ++k) {
            int idx = t + k * 256;
            int jl = idx >> 5, c4 = idx & 31;
            float4 w = reinterpret_cast<const float4*>(z + ((size_t)(b * NN + jb + jl)) * DD)[c4];
            float* p = &zl[jl * 129 + c4 * 4];
            p[0] = w.x; p[1] = w.y; p[2] = w.z; p[3] = w.w;
        }
        __syncthreads();
#pragma unroll
        for (int k = 0; k < 4; ++k) {
            int sid = t + k * 256;
            int blk = sid >> 6, s = sid & 63;
            int ktl = blk >> 3, nt = blk & 7;
            int d = nt * 16 + (s & 15);
            int jl = ktl * 32 + ((s >> 4) & 3) * 8;
            short8v o;
#pragma unroll
            for (int e = 0; e < 8; ++e) o[e] = f2bf(zl[(jl + e) * 129 + d]);
            *reinterpret_cast<short8v*>(zq + ((size_t)((b * 64 + jt * 2 + ktl) * 8 + nt) * 64 + s) * 8) = o;
        }
    } else {
        int v = bid - 768;
        int q = t & 15;
#pragma unroll
        for (int p = 0; p < 4; ++p) {
            int row = v * 64 + p * 16 + (t >> 4);
            float4 rv = reinterpret_cast<const float4*>(emb + (size_t)row * EE)[q];
            float a0 = __bfloat162float(__float2bfloat16(rv.x));
            float a1 = __bfloat162float(__float2bfloat16(rv.y));
            float a2 = __bfloat162float(__float2bfloat16(rv.z));
            float a3 = __bfloat162float(__float2bfloat16(rv.w));
            float s2 = a0 * a0 + a1 * a1 + a2 * a2 + a3 * a3;
#pragma unroll
            for (int off = 1; off < 16; off <<= 1) s2 += __shfl_xor(s2, off);
            if (q == 0) sq[row] = s2;
        }
    }
}

// ---------------- main MFMA attention: barrier-free streaming + in-block j-split ----------------
// grid: bid = ((js*32 + it))*8 + b (XCD-pinned batch) = 1024 blocks = 4 blocks/CU.
// Block = 64 rows x 1 js-slice. 4 waves = 2 row-halves (h=w>>1, 32 rows each, m=0,1)
// x 2 j-subranges (u=w&1, half the tiles each) -> 2x occupancy at IDENTICAL L2 traffic
// vs 128-row blocks. Epilogue: j-sub pairs combine acc+dsum through the dead P^T LDS
// (two 8KB chunks, contiguous-lane b128), then u=0 waves write partials.
// QK (swapped): lane (g,c), group m holds S[i=rows+m*16+c][j=J*16+4g+r]; direct-from-L2
// operand reads; vote-before-exp (p<1e-6 truncation, bounded out err < ~0.011).
__global__ __launch_bounds__(256, 4) void attn_mfma(const short* __restrict__ embq,
                                                    const short* __restrict__ zq,
                                                    const float* __restrict__ sq,
                                                    float* __restrict__ outnum,
                                                    float* __restrict__ den,
                                                    int njs) {
    __shared__ short sU[4][2048];     // 16KB: per-wave P^T scratch; reused as acc-combine staging
    __shared__ float sDn[2][2][64];   // dsum combine

    const int t = threadIdx.x;
    const int bid = blockIdx.x;
    const int b = bid & 7;
    const int q = bid >> 3;
    const int it = q & 31;
    const int js = q >> 5;
    const int ib = it * 64;
    const int w = t >> 6;
    const int h = w >> 1;   // row half (32 rows)
    const int u = w & 1;    // j-subrange
    const int l = t & 63;
    const int g = (l >> 4) & 3;
    const int c = l & 15;

    const short8v* embq8 = (const short8v*)embq;
    const short8v* zq8 = (const short8v*)zq;
    const float* sqB = sq + b * NN;

    const int ntW = (32 / njs) >> 1;        // tiles per wave
    const int jtW0 = js * (32 / njs) + u * ntW;
    const int jtEnd = jtW0 + ntW;

    // this wave's I fragments (B operand of swapped QK), straight from global (L2)
    short8v qkB[2][2];
#pragma unroll
    for (int m = 0; m < 2; ++m)
#pragma unroll
        for (int ke = 0; ke < 2; ++ke)
            qkB[m][ke] = embq8[((size_t)(b * 128 + it * 4 + h * 2 + m) * 2 + ke) * 64 + l];
    float sqi[2];
#pragma unroll
    for (int m = 0; m < 2; ++m) sqi[m] = sqB[ib + h * 32 + m * 16 + c];

    float dsum[2] = {0.f, 0.f};
    float4v acc[2][8];
#pragma unroll
    for (int m = 0; m < 2; ++m)
#pragma unroll
        for (int nt = 0; nt < 8; ++nt) acc[m][nt] = (float4v){0.f, 0.f, 0.f, 0.f};

    char* ptw = (char*)&sU[w][0];
    const int swz = (c & 7) << 4;

    for (int jt = jtW0; jt < jtEnd; ++jt) {
        // ---- issue all of this tile's loads up front (L2 hits, ILP) ----
        short8v a[4][2];
        float4 sqj[4];
#pragma unroll
        for (int J = 0; J < 4; ++J) {
            a[J][0] = embq8[((size_t)(b * 128 + jt * 4 + J) * 2 + 0) * 64 + l];
            a[J][1] = embq8[((size_t)(b * 128 + jt * 4 + J) * 2 + 1) * 64 + l];
            sqj[J] = *reinterpret_cast<const float4*>(sqB + jt * 64 + J * 16 + 4 * g);
        }

        bool anyLive = false;
#pragma unroll
        for (int J = 0; J < 4; ++J) {
            float d2[2][4];
            float mn = 1e30f;
#pragma unroll
            for (int m = 0; m < 2; ++m) {
                float4v sfr = (float4v){0.f, 0.f, 0.f, 0.f};
                sfr = __builtin_amdgcn_mfma_f32_16x16x32_bf16(a[J][0], qkB[m][0], sfr, 0, 0, 0);
                sfr = __builtin_amdgcn_mfma_f32_16x16x32_bf16(a[J][1], qkB[m][1], sfr, 0, 0, 0);
                d2[m][0] = fmaxf(fmaf(-2.0f, sfr[0], sqi[m] + sqj[J].x), 0.0f);
                d2[m][1] = fmaxf(fmaf(-2.0f, sfr[1], sqi[m] + sqj[J].y), 0.0f);
                d2[m][2] = fmaxf(fmaf(-2.0f, sfr[2], sqi[m] + sqj[J].z), 0.0f);
                d2[m][3] = fmaxf(fmaf(-2.0f, sfr[3], sqi[m] + sqj[J].w), 0.0f);
                mn = fminf(mn, fminf(fminf(d2[m][0], d2[m][1]), fminf(d2[m][2], d2[m][3])));
            }
            const bool live = !__all(mn > 13.8f);  // wave-uniform
#pragma unroll
            for (int m = 0; m < 2; ++m) {
                unsigned long long pword = 0ull;
                if (live) {
                    float p0 = __expf(-d2[m][0]);
                    float p1 = __expf(-d2[m][1]);
                    float p2 = __expf(-d2[m][2]);
                    float p3 = __expf(-d2[m][3]);
                    dsum[m] += (p0 + p1) + (p2 + p3);
                    pword = (unsigned long long)pack2bf(p0, p1) |
                            ((unsigned long long)pack2bf(p2, p3) << 32);
                }
                // must write even when dead: PV (if tile live) reads every slot
                *reinterpret_cast<unsigned long long*>(
                    ptw + ((m * 2048 + c * 128 + g * 8) ^ swz ^ (J * 32))) = pword;
            }
            anyLive |= live;
        }

        // ---- PV only when some J in this tile carries mass ----
        if (anyLive) {
            short8v pa[2][2];
#pragma unroll
            for (int m = 0; m < 2; ++m)
#pragma unroll
                for (int kt = 0; kt < 2; ++kt)
                    pa[m][kt] = *reinterpret_cast<const short8v*>(
                        ptw + ((m * 2048 + c * 128 + kt * 64 + g * 16) ^ swz));
#pragma unroll
            for (int nt = 0; nt < 8; ++nt) {
                short8v z0 = zq8[(size_t)((b * 64 + jt * 2 + 0) * 8 + nt) * 64 + l];
                short8v z1 = zq8[(size_t)((b * 64 + jt * 2 + 1) * 8 + nt) * 64 + l];
#pragma unroll
                for (int m = 0; m < 2; ++m) {
                    acc[m][nt] = __builtin_amdgcn_mfma_f32_16x16x32_bf16(pa[m][0], z0, acc[m][nt], 0, 0, 0);
                    acc[m][nt] = __builtin_amdgcn_mfma_f32_16x16x32_bf16(pa[m][1], z1, acc[m][nt], 0, 0, 0);
                }
            }
        }
    }

    // dsum reduce over g-groups -> all lanes hold row (m, c) sums for this wave's j-sub
#pragma unroll
    for (int m = 0; m < 2; ++m) {
        dsum[m] += __shfl_xor(dsum[m], 16);
        dsum[m] += __shfl_xor(dsum[m], 32);
    }

    // ---- combine j-sub pairs (u=1 -> u=0) through LDS; P^T region is dead now ----
    float4v* sF = reinterpret_cast<float4v*>(&sU[0][0]);  // 1024 float4 slots (16KB)
    __syncthreads();
    if (u == 1) {
#pragma unroll
        for (int m = 0; m < 2; ++m) sDn[h][m][l] = dsum[m];
#pragma unroll
        for (int nt = 0; nt < 8; ++nt) sF[h * 512 + nt * 64 + l] = acc[0][nt];
    }
    __syncthreads();
    if (u == 0) {
#pragma unroll
        for (int m = 0; m < 2; ++m) dsum[m] += sDn[h][m][l];
#pragma unroll
        for (int nt = 0; nt < 8; ++nt) acc[0][nt] += sF[h * 512 + nt * 64 + l];
    }
    __syncthreads();
    if (u == 1) {
#pragma unroll
        for (int nt = 0; nt < 8; ++nt) sF[h * 512 + nt * 64 + l] = acc[1][nt];
    }
    __syncthreads();
    if (u == 1) return;
#pragma unroll
    for (int nt = 0; nt < 8; ++nt) acc[1][nt] += sF[h * 512 + nt * 64 + l];

    // ---- epilogue (u=0 waves, rows ib + h*32 .. +32) ----
    if (njs == 1) {
#pragma unroll
        for (int m = 0; m < 2; ++m) {
            float invr[4];
#pragma unroll
            for (int r = 0; r < 4; ++r) invr[r] = 1.0f / __shfl(dsum[m], 4 * g + r);
#pragma unroll
            for (int r = 0; r < 4; ++r) {
                size_t row = (size_t)(b * NN + ib + h * 32 + m * 16 + 4 * g + r);
#pragma unroll
                for (int nt = 0; nt < 8; ++nt)
                    outnum[row * DD + nt * 16 + c] = acc[m][nt][r] * invr[r];
            }
        }
    } else {
        if (l < 16) {
            den[(size_t)js * BN + b * NN + ib + h * 32 + l] = dsum[0];
            den[(size_t)js * BN + b * NN + ib + h * 32 + 16 + l] = dsum[1];
        }
        // skip num writes when this row-half's whole j-slice carries no mass
        if (!__all(fmaxf(dsum[0], dsum[1]) < 1e-6f)) {
#pragma unroll
            for (int m = 0; m < 2; ++m)
#pragma unroll
                for (int r = 0; r < 4; ++r) {
                    size_t row = (size_t)js * BN + b * NN + ib + h * 32 + m * 16 + 4 * g + r;
#pragma unroll
                    for (int nt = 0; nt < 8; ++nt)
                        outnum[row * DD + nt * 16 + c] = acc[m][nt][r];
                }
        }
    }
}

// ---------------- reduce: out = sum_js num / sum_js den, num reads gated by den ----------------
__global__ __launch_bounds__(256) void reduce_kernel(const float4* __restrict__ num,
                                                     const float* __restrict__ den,
                                                     float4* __restrict__ out,
                                                     int njs) {
    int i4 = blockIdx.x * 256 + threadIdx.x;
    int row = i4 >> 5;
    float4 ns = make_float4(0.f, 0.f, 0.f, 0.f);
    float ds = 0.f;
    for (int js = 0; js < njs; ++js) {
        float dj = den[(size_t)js * BN + row];
        ds += dj;
        if (dj >= 1e-6f) {
            float4 v = num[(size_t)js * ((size_t)BN * (DD / 4)) + i4];
            ns.x += v.x; ns.y += v.y; ns.z += v.z; ns.w += v.w;
        }
    }
    float inv = 1.0f / ds;
    out[i4] = make_float4(ns.x * inv, ns.y * inv, ns.z * inv, ns.w * inv);
}

extern "C" void kernel_launch(void* const* d_in, const int* in_sizes, int n_in,
                              void* d_out, int out_size, void* d_ws, size_t ws_size,
                              hipStream_t stream) {
    (void)in_sizes; (void)n_in; (void)out_size;
    const float* emb = (const float*)d_in[0];
    const float* z = (const float*)d_in[1];
    float* out = (float*)d_out;
    float* ws = (float*)d_ws;

    // ws layout (floats): sq[BN] | den[njs*BN] | num[njs*BN*DD] | embq(1M shorts) | zq(2M shorts)
    int njs = 1;
    if (ws_size >= 40ull * 1024 * 1024) njs = 4;
    else if (ws_size >= 24ull * 1024 * 1024) njs = 2;

    float* sqw = ws;
    float* denw = ws + BN;
    float* numw = denw + (size_t)njs * BN;
    size_t numFloats = (njs > 1) ? (size_t)njs * BN * DD : 0;
    short* embqw = (short*)(numw + numFloats);
    short* zqw = embqw + (size_t)BB * NN * EE;

    prep_kernel<<<1024, 256, 0, stream>>>(emb, z, embqw, zqw, sqw);

    attn_mfma<<<8 * 32 * njs, 256, 0, stream>>>(embqw, zqw, sqw,
                                                njs == 1 ? out : numw, denw, njs);

    if (njs > 1) {
        reduce_kernel<<<(BN * (DD / 4)) / 256, 256, 0, stream>>>(
            (const float4*)numw, denw, (float4*)out, njs);
    }
}

// Round 17
// 31.023 us; speedup vs baseline: 1.6676x; 1.4081x over previous
//
#include <hip/hip_runtime.h>
#include <hip/hip_bf16.h>

#define BB 8
#define NN 2048
#define EE 64
#define DD 128
#define BN (BB * NN)

typedef __attribute__((ext_vector_type(8))) short short8v;
typedef __attribute__((ext_vector_type(4))) float float4v;

__device__ __forceinline__ short f2bf(float f) {
    __hip_bfloat16 h = __float2bfloat16(f);
    return *reinterpret_cast<short*>(&h);
}
__device__ __forceinline__ uint32_t pack2bf(float a, float b) {
    return (uint32_t)(uint16_t)f2bf(a) | ((uint32_t)(uint16_t)f2bf(b) << 16);
}

// ---------------- fused prep: embq | zq | sq ----------------
__global__ __launch_bounds__(256) void prep_kernel(const float* __restrict__ emb,
                                                   const float* __restrict__ z,
                                                   short* __restrict__ embq,
                                                   short* __restrict__ zq,
                                                   float* __restrict__ sq) {
    __shared__ float zl[64 * 129];
    const int bid = blockIdx.x;
    const int t = threadIdx.x;

    if (bid < 512) {
        int gid = bid * 256 + t;
        int s = gid & 63;
        int ke = (gid >> 6) & 1;
        int r16 = (gid >> 7) & 127;
        int b = gid >> 14;
        int i = r16 * 16 + (s & 15);
        int e0 = ke * 32 + ((s >> 4) & 3) * 8;
        const float4* src = reinterpret_cast<const float4*>(emb + ((size_t)(b * NN + i)) * EE + e0);
        float4 v0 = src[0], v1 = src[1];
        short8v o;
        o[0] = f2bf(v0.x); o[1] = f2bf(v0.y); o[2] = f2bf(v0.z); o[3] = f2bf(v0.w);
        o[4] = f2bf(v1.x); o[5] = f2bf(v1.y); o[6] = f2bf(v1.z); o[7] = f2bf(v1.w);
        *reinterpret_cast<short8v*>(embq + (size_t)gid * 8) = o;
    } else if (bid < 768) {
        int v = bid - 512;  // b*32 + jt
        int b = v >> 5;
        int jt = v & 31;
        int jb = jt * 64;
#pragma unroll
        for (int k = 0; k < 8; ++k) {
            int idx = t + k * 256;
            int jl = idx >> 5, c4 = idx & 31;
            float4 w = reinterpret_cast<const float4*>(z + ((size_t)(b * NN + jb + jl)) * DD)[c4];
            float* p = &zl[jl * 129 + c4 * 4];
            p[0] = w.x; p[1] = w.y; p[2] = w.z; p[3] = w.w;
        }
        __syncthreads();
#pragma unroll
        for (int k = 0; k < 4; ++k) {
            int sid = t + k * 256;
            int blk = sid >> 6, s = sid & 63;
            int ktl = blk >> 3, nt = blk & 7;
            int d = nt * 16 + (s & 15);
            int jl = ktl * 32 + ((s >> 4) & 3) * 8;
            short8v o;
#pragma unroll
            for (int e = 0; e < 8; ++e) o[e] = f2bf(zl[(jl + e) * 129 + d]);
            *reinterpret_cast<short8v*>(zq + ((size_t)((b * 64 + jt * 2 + ktl) * 8 + nt) * 64 + s) * 8) = o;
        }
    } else {
        int v = bid - 768;
        int q = t & 15;
#pragma unroll
        for (int p = 0; p < 4; ++p) {
            int row = v * 64 + p * 16 + (t >> 4);
            float4 rv = reinterpret_cast<const float4*>(emb + (size_t)row * EE)[q];
            float a0 = __bfloat162float(__float2bfloat16(rv.x));
            float a1 = __bfloat162float(__float2bfloat16(rv.y));
            float a2 = __bfloat162float(__float2bfloat16(rv.z));
            float a3 = __bfloat162float(__float2bfloat16(rv.w));
            float s2 = a0 * a0 + a1 * a1 + a2 * a2 + a3 * a3;
#pragma unroll
            for (int off = 1; off < 16; off <<= 1) s2 += __shfl_xor(s2, off);
            if (q == 0) sq[row] = s2;
        }
    }
}

// 8 fragment loads for one 64-j tile, immediate offsets off two base pointers
#define LOADA(dst, basep)                                                      \
    do {                                                                       \
        const char* _b0 = (basep);                                             \
        const char* _b1 = (basep) + 4096;                                      \
        dst[0][0] = *reinterpret_cast<const short8v*>(_b0);                    \
        dst[0][1] = *reinterpret_cast<const short8v*>(_b0 + 1024);             \
        dst[1][0] = *reinterpret_cast<const short8v*>(_b0 + 2048);             \
        dst[1][1] = *reinterpret_cast<const short8v*>(_b0 + 3072);             \
        dst[2][0] = *reinterpret_cast<const short8v*>(_b1);                    \
        dst[2][1] = *reinterpret_cast<const short8v*>(_b1 + 1024);             \
        dst[3][0] = *reinterpret_cast<const short8v*>(_b1 + 2048);             \
        dst[3][1] = *reinterpret_cast<const short8v*>(_b1 + 3072);             \
    } while (0)

// ---------------- main MFMA attention: barrier-free streaming, VALU-thin ----------------
// grid: bid = ((js*16 + it))*8 + b (XCD-pinned batch). 4 INDEPENDENT waves/block;
// wave owns 32 rows (m=0,1). Operands straight from global (L2-resident); only LDS
// use is the wave-private P^T transpose. Register ping-pong prefetch across tiles.
// Vote uses a conservative LOWER BOUND on d2min (bound = sqi + min_r sqj - 2*max_r sfr
// <= every d2), so __all(bound > 13.8) still proves all p < 1e-6 -> safe skip
// (bounded truncation, out err < ~0.011 worst case); false-lives just do extra exp.
__global__ __launch_bounds__(256, 2) void attn_mfma(const short* __restrict__ embq,
                                                    const short* __restrict__ zq,
                                                    const float* __restrict__ sq,
                                                    float* __restrict__ outnum,
                                                    float* __restrict__ den,
                                                    int njs) {
    __shared__ short sU[4][2048];  // 16KB: per-wave P^T scratch only (wave-private)

    const int t = threadIdx.x;
    const int bid = blockIdx.x;
    const int b = bid & 7;
    const int q = bid >> 3;
    const int it = q & 15;
    const int js = q >> 4;
    const int ib = it * 128;
    const int w = t >> 6;
    const int l = t & 63;
    const int g = (l >> 4) & 3;
    const int c = l & 15;

    const short8v* embq8 = (const short8v*)embq;
    const short8v* zq8 = (const short8v*)zq;
    const float* sqB = sq + b * NN;

    const int ntW = 32 / njs;  // 8 / 16 / 32 tiles (always even)
    const int jt0 = js * ntW;

    // this wave's I fragments (B operand of swapped QK)
    short8v qkB[2][2];
#pragma unroll
    for (int m = 0; m < 2; ++m)
#pragma unroll
        for (int ke = 0; ke < 2; ++ke)
            qkB[m][ke] = embq8[((size_t)(b * 128 + it * 8 + w * 2 + m) * 2 + ke) * 64 + l];
    float sqi[2];
#pragma unroll
    for (int m = 0; m < 2; ++m) sqi[m] = sqB[ib + w * 32 + m * 16 + c];

    float dsum[2] = {0.f, 0.f};
    float4v acc[2][8];
#pragma unroll
    for (int m = 0; m < 2; ++m)
#pragma unroll
        for (int nt = 0; nt < 8; ++nt) acc[m][nt] = (float4v){0.f, 0.f, 0.f, 0.f};

    char* ptw = (char*)&sU[w][0];
    const int swz = (c & 7) << 4;

    auto computeTile = [&](int jt, short8v (&A)[4][2]) {
        const float* sqjp = sqB + jt * 64 + 4 * g;
        bool anyLive = false;
        float sfr[2][4];
        float4 sqj;
#pragma unroll
        for (int J = 0; J < 4; ++J) {
            sqj = *reinterpret_cast<const float4*>(sqjp + J * 16);
            float sqjmin = fminf(fminf(sqj.x, sqj.y), fminf(sqj.z, sqj.w));
            float bnd = 1e30f;
#pragma unroll
            for (int m = 0; m < 2; ++m) {
                float4v sf = (float4v){0.f, 0.f, 0.f, 0.f};
                sf = __builtin_amdgcn_mfma_f32_16x16x32_bf16(A[J][0], qkB[m][0], sf, 0, 0, 0);
                sf = __builtin_amdgcn_mfma_f32_16x16x32_bf16(A[J][1], qkB[m][1], sf, 0, 0, 0);
                sfr[m][0] = sf[0]; sfr[m][1] = sf[1]; sfr[m][2] = sf[2]; sfr[m][3] = sf[3];
                float smax = fmaxf(fmaxf(sf[0], sf[1]), fmaxf(sf[2], sf[3]));
                bnd = fminf(bnd, fmaf(-2.0f, smax, sqi[m] + sqjmin));
            }
            const bool liveJ = !__all(bnd > 13.8f);  // wave-uniform, conservative
#pragma unroll
            for (int m = 0; m < 2; ++m) {
                unsigned long long pword = 0ull;
                if (liveJ) {
                    float d0 = fmaxf(fmaf(-2.0f, sfr[m][0], sqi[m] + sqj.x), 0.0f);
                    float d1 = fmaxf(fmaf(-2.0f, sfr[m][1], sqi[m] + sqj.y), 0.0f);
                    float d2_ = fmaxf(fmaf(-2.0f, sfr[m][2], sqi[m] + sqj.z), 0.0f);
                    float d3 = fmaxf(fmaf(-2.0f, sfr[m][3], sqi[m] + sqj.w), 0.0f);
                    float p0 = __expf(-d0);
                    float p1 = __expf(-d1);
                    float p2 = __expf(-d2_);
                    float p3 = __expf(-d3);
                    dsum[m] += (p0 + p1) + (p2 + p3);
                    pword = (unsigned long long)pack2bf(p0, p1) |
                            ((unsigned long long)pack2bf(p2, p3) << 32);
                }
                // write even when dead: PV (if tile live) reads every slot
                *reinterpret_cast<unsigned long long*>(
                    ptw + ((m * 2048 + c * 128 + g * 8) ^ swz ^ (J * 32))) = pword;
            }
            anyLive |= liveJ;
        }

        if (anyLive) {
            short8v pa[2][2];
#pragma unroll
            for (int m = 0; m < 2; ++m)
#pragma unroll
                for (int kt = 0; kt < 2; ++kt)
                    pa[m][kt] = *reinterpret_cast<const short8v*>(
                        ptw + ((m * 2048 + c * 128 + kt * 64 + g * 16) ^ swz));
#pragma unroll
            for (int nt = 0; nt < 8; ++nt) {
                short8v z0 = zq8[(size_t)((b * 64 + jt * 2 + 0) * 8 + nt) * 64 + l];
                short8v z1 = zq8[(size_t)((b * 64 + jt * 2 + 1) * 8 + nt) * 64 + l];
#pragma unroll
                for (int m = 0; m < 2; ++m) {
                    acc[m][nt] = __builtin_amdgcn_mfma_f32_16x16x32_bf16(pa[m][0], z0, acc[m][nt], 0, 0, 0);
                    acc[m][nt] = __builtin_amdgcn_mfma_f32_16x16x32_bf16(pa[m][1], z1, acc[m][nt], 0, 0, 0);
                }
            }
        }
    };

    // embq tile base pointer (includes lane offset); stride 8192 B per 64-j tile.
    // Final prefetch may read one tile past the slice: stays inside d_ws (embq is
    // followed by zq) and the values are never consumed.
    const char* pa = (const char*)embq8 + (((size_t)(b * 128 + jt0 * 4) * 2) * 64 + l) * 16;

    short8v A0[4][2], A1[4][2];
    LOADA(A0, pa);  // tile jt0

    for (int jp = 0; jp < ntW / 2; ++jp) {
        const int jt = jt0 + 2 * jp;
        pa += 8192;
        LOADA(A1, pa);        // prefetch jt+1 while computing jt
        computeTile(jt, A0);
        pa += 8192;
        LOADA(A0, pa);        // prefetch jt+2 while computing jt+1
        computeTile(jt + 1, A1);
    }

    // dsum reduce over g-groups -> all lanes hold row (m, c) sums
#pragma unroll
    for (int m = 0; m < 2; ++m) {
        dsum[m] += __shfl_xor(dsum[m], 16);
        dsum[m] += __shfl_xor(dsum[m], 32);
    }

    if (njs == 1) {
#pragma unroll
        for (int m = 0; m < 2; ++m) {
            float invr[4];
#pragma unroll
            for (int r = 0; r < 4; ++r) invr[r] = 1.0f / __shfl(dsum[m], 4 * g + r);
#pragma unroll
            for (int r = 0; r < 4; ++r) {
                size_t row = (size_t)(b * NN + ib + w * 32 + m * 16 + 4 * g + r);
#pragma unroll
                for (int nt = 0; nt < 8; ++nt)
                    outnum[row * DD + nt * 16 + c] = acc[m][nt][r] * invr[r];
            }
        }
    } else {
        if (l < 16) {
            den[(size_t)js * BN + b * NN + ib + w * 32 + l] = dsum[0];
            den[(size_t)js * BN + b * NN + ib + w * 32 + 16 + l] = dsum[1];
        }
        // skip num writes when this wave's whole j-slice carries no mass
        if (!__all(fmaxf(dsum[0], dsum[1]) < 1e-6f)) {
#pragma unroll
            for (int m = 0; m < 2; ++m)
#pragma unroll
                for (int r = 0; r < 4; ++r) {
                    size_t row = (size_t)js * BN + b * NN + ib + w * 32 + m * 16 + 4 * g + r;
#pragma unroll
                    for (int nt = 0; nt < 8; ++nt)
                        outnum[row * DD + nt * 16 + c] = acc[m][nt][r];
                }
        }
    }
}

// ---------------- reduce: out = sum_js num / sum_js den, num reads gated by den ----------------
__global__ __launch_bounds__(256) void reduce_kernel(const float4* __restrict__ num,
                                                     const float* __restrict__ den,
                                                     float4* __restrict__ out,
                                                     int njs) {
    int i4 = blockIdx.x * 256 + threadIdx.x;
    int row = i4 >> 5;
    float4 ns = make_float4(0.f, 0.f, 0.f, 0.f);
    float ds = 0.f;
    for (int js = 0; js < njs; ++js) {
        float dj = den[(size_t)js * BN + row];
        ds += dj;
        if (dj >= 1e-6f) {
            float4 v = num[(size_t)js * ((size_t)BN * (DD / 4)) + i4];
            ns.x += v.x; ns.y += v.y; ns.z += v.z; ns.w += v.w;
        }
    }
    float inv = 1.0f / ds;
    out[i4] = make_float4(ns.x * inv, ns.y * inv, ns.z * inv, ns.w * inv);
}

extern "C" void kernel_launch(void* const* d_in, const int* in_sizes, int n_in,
                              void* d_out, int out_size, void* d_ws, size_t ws_size,
                              hipStream_t stream) {
    (void)in_sizes; (void)n_in; (void)out_size;
    const float* emb = (const float*)d_in[0];
    const float* z = (const float*)d_in[1];
    float* out = (float*)d_out;
    float* ws = (float*)d_ws;

    // ws layout (floats): sq[BN] | den[njs*BN] | num[njs*BN*DD] | embq(1M shorts) | zq(2M shorts)
    int njs = 1;
    if (ws_size >= 40ull * 1024 * 1024) njs = 4;
    else if (ws_size >= 24ull * 1024 * 1024) njs = 2;

    float* sqw = ws;
    float* denw = ws + BN;
    float* numw = denw + (size_t)njs * BN;
    size_t numFloats = (njs > 1) ? (size_t)njs * BN * DD : 0;
    short* embqw = (short*)(numw + numFloats);
    short* zqw = embqw + (size_t)BB * NN * EE;

    prep_kernel<<<1024, 256, 0, stream>>>(emb, z, embqw, zqw, sqw);

    attn_mfma<<<8 * 16 * njs, 256, 0, stream>>>(embqw, zqw, sqw,
                                                njs == 1 ? out : numw, denw, njs);

    if (njs > 1) {
        reduce_kernel<<<(BN * (DD / 4)) / 256, 256, 0, stream>>>(
            (const float4*)numw, denw, (float4*)out, njs);
    }
}